// Round 3
// baseline (235.448 us; speedup 1.0000x reference)
//
#include <hip/hip_runtime.h>
#include <hip/hip_bf16.h>

// ---------------------------------------------------------------------------
// GraphSAGE 2-layer, bf16-MFMA edition.
//   h   = relu( mean_nbr(x) @ W1l + x @ W1r + b1 )     (aggregate-first)
//   out = mean_nbr(h @ W2l) + h @ W2r + b2             (transform-first)
// R12: 16-lane-group gathers (128 chains/CU) won (-14us).
// R13: deg merged into prep; latency-bound atomics hide under streaming.
// R14: agg1 fused into fused12 staging (aggb round trip eliminated).
// R15: 4-deep gather MLP -- NO effect (R1 vs R15 within 5%) => gather is
// bound by the shared random-access path (L2-miss/L3), ~26 outstanding
// 256B req/CU achieved. Per-wave restructuring can't help.
// R16: (a) drop ws2 LDS staging -- W2 frags read direct from global
// (16KB, L2-broadcast-hot). LDS 52.2->34.8KB => 4 blocks/CU, 32 waves/CU;
// launch_bounds(512,8) pins regalloc <=64 VGPR. (b) combine2 -> 4-lane
// groups (64 chains/block; its 6.4MB z2b working set is L2-resident, so
// it IS latency-bound, unlike fused12's gather).
// ---------------------------------------------------------------------------

#define FDIM 128
#define CDIM 32
#define SCAN_CHUNK 1024
#define PSTR 136        // padded LDS row stride in shorts (272B): 2-way bank
                        // aliasing for 16-row frag reads = free (m136)

typedef __attribute__((ext_vector_type(8))) short short8;
typedef __attribute__((ext_vector_type(4))) float f32x4;
typedef unsigned short ushort_t;
typedef unsigned int uint_t;

static __device__ __forceinline__ ushort_t f2bf(float f) {
    uint_t u = __float_as_uint(f);
    u += 0x7fffu + ((u >> 16) & 1u);       // round-to-nearest-even
    return (ushort_t)(u >> 16);
}
static __device__ __forceinline__ float bf2f_lo(uint_t u) {
    return __uint_as_float(u << 16);
}
static __device__ __forceinline__ float bf2f_hi(uint_t u) {
    return __uint_as_float(u & 0xffff0000u);
}

// ---- prep: deg atomics (blocks [0,DB4)) | x->bf16 | W transpose+cvt -------
// deg range FIRST so its latency-bound blocks overlap the streaming ranges.

__global__ __launch_bounds__(256) void prep_kernel(
        const int* __restrict__ dst, int* __restrict__ deg, int E, int n,
        const float* __restrict__ x, uint_t* __restrict__ xb4, long long total8,
        const float* __restrict__ W1l, const float* __restrict__ W1r,
        const float* __restrict__ W2l, const float* __restrict__ W2r,
        ushort_t* __restrict__ w1lt, ushort_t* __restrict__ w1rt,
        ushort_t* __restrict__ w2lt, ushort_t* __restrict__ w2rt,
        int DB4, int CB) {
    int b = (int)blockIdx.x;
    if (b < DB4) {
        int e0 = (b * 256 + threadIdx.x) * 4;
        if (e0 + 3 < E) {
            int4 d4 = *(const int4*)(dst + e0);
            if (d4.x >= 0 && d4.x < n) atomicAdd(&deg[d4.x], 1);
            if (d4.y >= 0 && d4.y < n) atomicAdd(&deg[d4.y], 1);
            if (d4.z >= 0 && d4.z < n) atomicAdd(&deg[d4.z], 1);
            if (d4.w >= 0 && d4.w < n) atomicAdd(&deg[d4.w], 1);
        } else {
            for (int e = e0; e < E; e++) {
                int d = dst[e];
                if (d >= 0 && d < n) atomicAdd(&deg[d], 1);
            }
        }
    } else if (b < DB4 + CB) {
        long long i = (long long)(b - DB4) * 256 + threadIdx.x;
        if (i >= total8) return;
        const float4* p = (const float4*)x + i * 2;
        float4 v0 = p[0], v1 = p[1];
        uint4 o;
        o.x = (uint_t)f2bf(v0.x) | ((uint_t)f2bf(v0.y) << 16);
        o.y = (uint_t)f2bf(v0.z) | ((uint_t)f2bf(v0.w) << 16);
        o.z = (uint_t)f2bf(v1.x) | ((uint_t)f2bf(v1.y) << 16);
        o.w = (uint_t)f2bf(v1.z) | ((uint_t)f2bf(v1.w) << 16);
        ((uint4*)xb4)[i] = o;
    } else {
        int idx = (b - DB4 - CB) * 256 + threadIdx.x;
        const float* w; ushort_t* wt; int Nc, local;
        if (idx < 16384)      { w = W1l; wt = w1lt; Nc = 128; local = idx; }
        else if (idx < 32768) { w = W1r; wt = w1rt; Nc = 128; local = idx - 16384; }
        else if (idx < 36864) { w = W2l; wt = w2lt; Nc = 32;  local = idx - 32768; }
        else if (idx < 40960) { w = W2r; wt = w2rt; Nc = 32;  local = idx - 36864; }
        else return;
        int nn = local >> 7, kk = local & 127;
        wt[nn * 128 + kk] = f2bf(w[kk * Nc + nn]);
    }
}

// ---- hierarchical scan (scan3 re-derives its block offset from partials) --

__global__ __launch_bounds__(256) void scan1_kernel(
        const int* __restrict__ deg, int* __restrict__ partials, int n) {
    __shared__ int red[256];
    int t = threadIdx.x;
    int base = blockIdx.x * SCAN_CHUNK + t * 4;
    int s = 0;
    if (base + 3 < n) {
        int4 v = *(const int4*)(deg + base);
        s = v.x + v.y + v.z + v.w;
    } else {
        for (int i = 0; i < 4; i++) if (base + i < n) s += deg[base + i];
    }
    red[t] = s;
    __syncthreads();
#pragma unroll
    for (int off = 128; off > 0; off >>= 1) {
        if (t < off) red[t] += red[t + off];
        __syncthreads();
    }
    if (t == 0) partials[blockIdx.x] = red[0];
}

// also seeds cursor[i] = rowptr[i] so fill needs no rowptr load
__global__ __launch_bounds__(256) void scan3_kernel(
        const int* __restrict__ deg, const int* __restrict__ partials,
        int* __restrict__ rowptr, int* __restrict__ cursor, int n, int SB) {
    __shared__ int s[256];
    int t = threadIdx.x;
    int pre = (t < SB && t < (int)blockIdx.x) ? partials[t] : 0;
    s[t] = pre;
    __syncthreads();
#pragma unroll
    for (int off = 128; off > 0; off >>= 1) {
        if (t < off) s[t] += s[t + off];
        __syncthreads();
    }
    int blockbase = s[0];
    __syncthreads();

    int base = blockIdx.x * SCAN_CHUNK + t * 4;
    int d0 = 0, d1 = 0, d2 = 0, d3 = 0;
    if (base + 3 < n) {
        int4 v = *(const int4*)(deg + base);
        d0 = v.x; d1 = v.y; d2 = v.z; d3 = v.w;
    } else {
        if (base + 0 < n) d0 = deg[base + 0];
        if (base + 1 < n) d1 = deg[base + 1];
        if (base + 2 < n) d2 = deg[base + 2];
        if (base + 3 < n) d3 = deg[base + 3];
    }
    s[t] = d0 + d1 + d2 + d3;
    __syncthreads();
#pragma unroll
    for (int off = 1; off < 256; off <<= 1) {
        int u = (t >= off) ? s[t - off] : 0;
        __syncthreads();
        s[t] += u;
        __syncthreads();
    }
    int run = blockbase + ((t == 0) ? 0 : s[t - 1]);
    int dd[4] = {d0, d1, d2, d3};
#pragma unroll
    for (int i = 0; i < 4; i++) {
        if (base + i < n) {
            rowptr[base + i] = run;
            cursor[base + i] = run;
            run += dd[i];
        }
    }
}

// ---- fill: 4 edges/thread; cursor pre-seeded with rowptr ------------------

__global__ void fill_kernel(const int* __restrict__ src, const int* __restrict__ dst,
                            int* __restrict__ cursor, int* __restrict__ nbr,
                            int E, int n) {
    int e0 = (blockIdx.x * 256 + threadIdx.x) * 4;
    if (e0 + 3 < E) {
        int4 s4 = *(const int4*)(src + e0);
        int4 d4 = *(const int4*)(dst + e0);
        if (d4.x >= 0 && d4.x < n) { int p = atomicAdd(&cursor[d4.x], 1); nbr[p] = s4.x; }
        if (d4.y >= 0 && d4.y < n) { int p = atomicAdd(&cursor[d4.y], 1); nbr[p] = s4.y; }
        if (d4.z >= 0 && d4.z < n) { int p = atomicAdd(&cursor[d4.z], 1); nbr[p] = s4.z; }
        if (d4.w >= 0 && d4.w < n) { int p = atomicAdd(&cursor[d4.w], 1); nbr[p] = s4.w; }
    } else {
        for (int e = e0; e < E; e++) {
            int d = dst[e];
            if (d >= 0 && d < n) { int p = atomicAdd(&cursor[d], 1); nbr[p] = src[e]; }
        }
    }
}

// ---- fused12: gather-agg + layer-1 GEMM + epilogue + layer-2 GEMM ---------
// 512 thr = 8 waves; tile = 64 rows; 34.8KB LDS -> 4 blocks/CU (R16).
// Gather: each 16-lane group walks rows (grp, grp+32) simultaneously,
// 2-deep each = 4 loads in flight; predicated loads zero-fill (exact).
// Layer-2 W2 frags read straight from global (16KB, L2-broadcast-hot).

__global__ __launch_bounds__(512, 8) void fused12_kernel(
        const ushort_t* __restrict__ xb,
        const int* __restrict__ rowptr, const int* __restrict__ deg,
        const int* __restrict__ nbr,
        const ushort_t* __restrict__ w1lt, const ushort_t* __restrict__ w1rt,
        const ushort_t* __restrict__ w2lt, const ushort_t* __restrict__ w2rt,
        const float* __restrict__ b1,
        ushort_t* __restrict__ z2b, float* __restrict__ r2, int n) {
    __shared__ ushort_t xs[64 * PSTR];          // x tile; becomes hs after layer 1
    __shared__ ushort_t as_[64 * PSTR];         // agg tile (gathered in-kernel)

    const int t    = threadIdx.x;
    const int wave = t >> 6;            // 0..7
    const int lane = t & 63;
    const int quad = lane >> 4;
    const int l16  = lane & 15;
    const int row0 = blockIdx.x * 64;
    const int c1   = wave * 16;         // layer-1 col tile

    const uint_t* xbu = (const uint_t*)xb;

    // stage xb tile: 1024 16B chunks, 2 per thread, coalesced
#pragma unroll
    for (int it = 0; it < 2; it++) {
        int c   = t + it * 512;
        int row = c >> 4, col = c & 15;
        int grow = row0 + row; if (grow >= n) grow = n - 1;   // clamp; stores guarded
        size_t goff = (size_t)grow * FDIM + col * 8;
        *(short8*)(xs + row * PSTR + col * 8) = *(const short8*)(xb + goff);
    }

    // gather-aggregate mean_nbr(x) -> as_ : rows grp and grp+32 walked
    // simultaneously, 2-deep each (4 outstanding gathers per group).
    const int grp = t >> 4;             // 0..31
    {
        const int iA = row0 + grp;
        const int iB = row0 + grp + 32;
        int stA = 0, dA = 0, stB = 0, dB = 0;
        if (iA < n) { stA = rowptr[iA]; dA = deg[iA]; }
        if (iB < n) { stB = rowptr[iB]; dB = deg[iB]; }
        float sA[8] = {0.f,0.f,0.f,0.f,0.f,0.f,0.f,0.f};
        float sB[8] = {0.f,0.f,0.f,0.f,0.f,0.f,0.f,0.f};
        const int m = dA > dB ? dA : dB;
        const uint4 uz = {0u, 0u, 0u, 0u};
        for (int e = 0; e < m; e += 2) {
            uint4 uA0 = uz, uA1 = uz, uB0 = uz, uB1 = uz;
            if (e     < dA) uA0 = *(const uint4*)(xbu + (size_t)nbr[stA + e    ] * 64 + l16 * 4);
            if (e + 1 < dA) uA1 = *(const uint4*)(xbu + (size_t)nbr[stA + e + 1] * 64 + l16 * 4);
            if (e     < dB) uB0 = *(const uint4*)(xbu + (size_t)nbr[stB + e    ] * 64 + l16 * 4);
            if (e + 1 < dB) uB1 = *(const uint4*)(xbu + (size_t)nbr[stB + e + 1] * 64 + l16 * 4);
            sA[0] += bf2f_lo(uA0.x) + bf2f_lo(uA1.x); sA[1] += bf2f_hi(uA0.x) + bf2f_hi(uA1.x);
            sA[2] += bf2f_lo(uA0.y) + bf2f_lo(uA1.y); sA[3] += bf2f_hi(uA0.y) + bf2f_hi(uA1.y);
            sA[4] += bf2f_lo(uA0.z) + bf2f_lo(uA1.z); sA[5] += bf2f_hi(uA0.z) + bf2f_hi(uA1.z);
            sA[6] += bf2f_lo(uA0.w) + bf2f_lo(uA1.w); sA[7] += bf2f_hi(uA0.w) + bf2f_hi(uA1.w);
            sB[0] += bf2f_lo(uB0.x) + bf2f_lo(uB1.x); sB[1] += bf2f_hi(uB0.x) + bf2f_hi(uB1.x);
            sB[2] += bf2f_lo(uB0.y) + bf2f_lo(uB1.y); sB[3] += bf2f_hi(uB0.y) + bf2f_hi(uB1.y);
            sB[4] += bf2f_lo(uB0.z) + bf2f_lo(uB1.z); sB[5] += bf2f_hi(uB0.z) + bf2f_hi(uB1.z);
            sB[6] += bf2f_lo(uB0.w) + bf2f_lo(uB1.w); sB[7] += bf2f_hi(uB0.w) + bf2f_hi(uB1.w);
        }
        float invA = 1.0f / (float)(dA > 0 ? dA : 1);
        float invB = 1.0f / (float)(dB > 0 ? dB : 1);
        uint4 oA, oB;
        oA.x = (uint_t)f2bf(sA[0] * invA) | ((uint_t)f2bf(sA[1] * invA) << 16);
        oA.y = (uint_t)f2bf(sA[2] * invA) | ((uint_t)f2bf(sA[3] * invA) << 16);
        oA.z = (uint_t)f2bf(sA[4] * invA) | ((uint_t)f2bf(sA[5] * invA) << 16);
        oA.w = (uint_t)f2bf(sA[6] * invA) | ((uint_t)f2bf(sA[7] * invA) << 16);
        oB.x = (uint_t)f2bf(sB[0] * invB) | ((uint_t)f2bf(sB[1] * invB) << 16);
        oB.y = (uint_t)f2bf(sB[2] * invB) | ((uint_t)f2bf(sB[3] * invB) << 16);
        oB.z = (uint_t)f2bf(sB[4] * invB) | ((uint_t)f2bf(sB[5] * invB) << 16);
        oB.w = (uint_t)f2bf(sB[6] * invB) | ((uint_t)f2bf(sB[7] * invB) << 16);
        *(uint4*)(as_ + grp * PSTR + l16 * 8) = oA;        // 272B rows, 16B aligned
        *(uint4*)(as_ + (grp + 32) * PSTR + l16 * 8) = oB;
    }

    // W1 B-frags for this wave's 16 cols -> registers (L2-resident).
    short8 bl1[4], br1[4];
#pragma unroll
    for (int k = 0; k < 4; k++) {
        size_t woff = (size_t)(c1 + l16) * FDIM + k * 32 + quad * 8;
        bl1[k] = *(const short8*)(w1lt + woff);
        br1[k] = *(const short8*)(w1rt + woff);
    }
    float b1c = b1[c1 + l16];

    __syncthreads();

    // ---- layer 1: A-frags from LDS ----
    f32x4 acc1[4];
#pragma unroll
    for (int r = 0; r < 4; r++) acc1[r] = (f32x4){0.f, 0.f, 0.f, 0.f};

#pragma unroll
    for (int k = 0; k < 4; k++) {
        short8 a1[4], a2[4];
#pragma unroll
        for (int r = 0; r < 4; r++) {
            int lro = (r * 16 + l16) * PSTR + k * 32 + quad * 8;
            a1[r] = *(const short8*)(as_ + lro);
            a2[r] = *(const short8*)(xs  + lro);
        }
#pragma unroll
        for (int r = 0; r < 4; r++) {
            acc1[r] = __builtin_amdgcn_mfma_f32_16x16x32_bf16(a1[r], bl1[k], acc1[r], 0, 0, 0);
            acc1[r] = __builtin_amdgcn_mfma_f32_16x16x32_bf16(a2[r], br1[k], acc1[r], 0, 0, 0);
        }
    }

    __syncthreads();          // all waves done reading xs before hs overwrite

    // epilogue -> hs (= xs). C/D: col = l16, row = quad*4 + reg.
    ushort_t* hs = xs;
#pragma unroll
    for (int r = 0; r < 4; r++)
#pragma unroll
        for (int reg = 0; reg < 4; reg++) {
            int lrow = r * 16 + quad * 4 + reg;
            float v = acc1[r][reg] + b1c;
            v = v > 0.f ? v : 0.f;
            hs[lrow * PSTR + c1 + l16] = f2bf(v);
        }

    __syncthreads();

    // ---- layer 2: W2 frags direct from global (L2-broadcast-hot) ----
    const int rs = (wave >> 1) * 16;    // row sub-tile
    const int c2 = (wave & 1) * 16;     // col tile
    f32x4 a2l = (f32x4){0.f, 0.f, 0.f, 0.f};
    f32x4 a2r = (f32x4){0.f, 0.f, 0.f, 0.f};
#pragma unroll
    for (int k = 0; k < 4; k++) {
        size_t woff = (size_t)(c2 + l16) * FDIM + k * 32 + quad * 8;
        short8 ah = *(const short8*)(hs + (rs + l16) * PSTR + k * 32 + quad * 8);
        short8 wl = *(const short8*)(w2lt + woff);
        short8 wr = *(const short8*)(w2rt + woff);
        a2l = __builtin_amdgcn_mfma_f32_16x16x32_bf16(ah, wl, a2l, 0, 0, 0);
        a2r = __builtin_amdgcn_mfma_f32_16x16x32_bf16(ah, wr, a2r, 0, 0, 0);
    }
#pragma unroll
    for (int reg = 0; reg < 4; reg++) {
        int grow = row0 + rs + quad * 4 + reg;
        if (grow < n) {
            z2b[(size_t)grow * CDIM + c2 + l16] = f2bf(a2l[reg]);
            r2 [(size_t)grow * CDIM + c2 + l16] = a2r[reg];
        }
    }
}

// ---- combine2: out = inv * sum_j z2b[j] + r2 + b2 -------------------------
// R16: ONE NODE PER 4-LANE GROUP (64 chains / 256-thr block): one uint4/lane
// covers the 64B z2b row. z2b (6.4MB) is L2-resident => latency-bound, so
// chain count is the lever here. Per-column accumulation order unchanged.

__global__ __launch_bounds__(256) void combine2_kernel(
        const uint_t* __restrict__ z2bu /* N x 16 uints */,
        const int* __restrict__ rowptr, const int* __restrict__ deg,
        const int* __restrict__ nbr, const float* __restrict__ b2,
        const float* __restrict__ r2, float* __restrict__ out, int n) {
    int t = threadIdx.x;
    int i = blockIdx.x * 64 + (t >> 2);
    if (i >= n) return;
    int l4 = t & 3;
    int start = rowptr[i];
    int d     = deg[i];
    float s0 = 0.f, s1 = 0.f, s2 = 0.f, s3 = 0.f;
    float s4 = 0.f, s5 = 0.f, s6 = 0.f, s7 = 0.f;
    int e = 0;
    for (; e + 1 < d; e += 2) {
        int j0 = nbr[start + e];
        int j1 = nbr[start + e + 1];
        uint4 u0 = *(const uint4*)(z2bu + (size_t)j0 * 16 + l4 * 4);
        uint4 u1 = *(const uint4*)(z2bu + (size_t)j1 * 16 + l4 * 4);
        s0 += bf2f_lo(u0.x) + bf2f_lo(u1.x); s1 += bf2f_hi(u0.x) + bf2f_hi(u1.x);
        s2 += bf2f_lo(u0.y) + bf2f_lo(u1.y); s3 += bf2f_hi(u0.y) + bf2f_hi(u1.y);
        s4 += bf2f_lo(u0.z) + bf2f_lo(u1.z); s5 += bf2f_hi(u0.z) + bf2f_hi(u1.z);
        s6 += bf2f_lo(u0.w) + bf2f_lo(u1.w); s7 += bf2f_hi(u0.w) + bf2f_hi(u1.w);
    }
    if (e < d) {
        int j = nbr[start + e];
        uint4 u = *(const uint4*)(z2bu + (size_t)j * 16 + l4 * 4);
        s0 += bf2f_lo(u.x); s1 += bf2f_hi(u.x);
        s2 += bf2f_lo(u.y); s3 += bf2f_hi(u.y);
        s4 += bf2f_lo(u.z); s5 += bf2f_hi(u.z);
        s6 += bf2f_lo(u.w); s7 += bf2f_hi(u.w);
    }
    float inv = 1.0f / (float)(d > 0 ? d : 1);
    float4 rr0 = *(const float4*)(r2 + (size_t)i * CDIM + l4 * 8);
    float4 rr1 = *(const float4*)(r2 + (size_t)i * CDIM + l4 * 8 + 4);
    float4 bb0 = *(const float4*)(b2 + l4 * 8);
    float4 bb1 = *(const float4*)(b2 + l4 * 8 + 4);
    float4 o0, o1;
    o0.x = s0 * inv + rr0.x + bb0.x;
    o0.y = s1 * inv + rr0.y + bb0.y;
    o0.z = s2 * inv + rr0.z + bb0.z;
    o0.w = s3 * inv + rr0.w + bb0.w;
    o1.x = s4 * inv + rr1.x + bb1.x;
    o1.y = s5 * inv + rr1.y + bb1.y;
    o1.z = s6 * inv + rr1.z + bb1.z;
    o1.w = s7 * inv + rr1.w + bb1.w;
    *(float4*)(out + (size_t)i * CDIM + l4 * 8) = o0;
    *(float4*)(out + (size_t)i * CDIM + l4 * 8 + 4) = o1;
}

// ---------------------------------------------------------------------------

extern "C" void kernel_launch(void* const* d_in, const int* in_sizes, int n_in,
                              void* d_out, int out_size, void* d_ws, size_t ws_size,
                              hipStream_t stream) {
    const float* x   = (const float*)d_in[0];
    const int*   ei  = (const int*)d_in[1];     // int64 in ref -> int32 here
    const float* W1l = (const float*)d_in[2];
    const float* b1  = (const float*)d_in[3];
    const float* W1r = (const float*)d_in[4];
    const float* W2l = (const float*)d_in[5];
    const float* b2  = (const float*)d_in[6];
    const float* W2r = (const float*)d_in[7];

    const int N = in_sizes[0] / FDIM;
    const int E = in_sizes[1] / 2;
    const int* src = ei;
    const int* dst = ei + E;

    char* p = (char*)d_ws;
    int*      deg      = (int*)p;      p += (size_t)N * sizeof(int);
    int*      cursor   = (int*)p;      p += (size_t)N * sizeof(int);
    int*      rowptr   = (int*)p;      p += (size_t)N * sizeof(int);
    int*      partials = (int*)p;      p += 256 * sizeof(int);
    ushort_t* w1lt     = (ushort_t*)p; p += FDIM * FDIM * sizeof(ushort_t);
    ushort_t* w1rt     = (ushort_t*)p; p += FDIM * FDIM * sizeof(ushort_t);
    ushort_t* w2lt     = (ushort_t*)p; p += FDIM * CDIM * sizeof(ushort_t);
    ushort_t* w2rt     = (ushort_t*)p; p += FDIM * CDIM * sizeof(ushort_t);
    int*      nbr      = (int*)p;      p += (size_t)((E + 3) / 4 * 4) * sizeof(int);
    ushort_t* xb       = (ushort_t*)p; p += (size_t)N * FDIM * sizeof(ushort_t);
    ushort_t* z2b      = (ushort_t*)p; p += (size_t)N * CDIM * sizeof(ushort_t);
    float*    r2       = (float*)p;    p += (size_t)N * CDIM * sizeof(float);

    const int SB = (N + SCAN_CHUNK - 1) / SCAN_CHUNK;
    const long long total8 = (long long)N * FDIM / 8;
    const int CB = (int)((total8 + 255) / 256);
    const int E4 = (E + 3) / 4;
    const int DB4 = (E4 + 255) / 256;
    const int WB = (40960 + 255) / 256;

    hipMemsetAsync(deg, 0, (size_t)N * sizeof(int), stream);  // cursor seeded by scan3

    prep_kernel <<<DB4 + CB + WB, 256, 0, stream>>>(dst, deg, E, N,
                                                    x, (uint_t*)xb, total8,
                                                    W1l, W1r, W2l, W2r,
                                                    w1lt, w1rt, w2lt, w2rt, DB4, CB);
    scan1_kernel<<<SB, 256, 0, stream>>>(deg, partials, N);
    scan3_kernel<<<SB, 256, 0, stream>>>(deg, partials, rowptr, cursor, N, SB);
    fill_kernel <<<DB4, 256, 0, stream>>>(src, dst, cursor, nbr, E, N);

    fused12_kernel<<<(N + 63) / 64, 512, 0, stream>>>(xb, rowptr, deg, nbr,
                                                      w1lt, w1rt, w2lt, w2rt,
                                                      b1, z2b, r2, N);
    combine2_kernel<<<(N + 63) / 64, 256, 0, stream>>>((const uint_t*)z2b, rowptr, deg, nbr,
                                                       b2, r2, (float*)d_out, N);
}

// Round 5
// 225.974 us; speedup vs baseline: 1.0419x; 1.0419x over previous
//
#include <hip/hip_runtime.h>
#include <hip/hip_bf16.h>

// ---------------------------------------------------------------------------
// GraphSAGE 2-layer, bf16-MFMA edition.
//   h   = relu( mean_nbr(x) @ W1l + x @ W1r + b1 )     (aggregate-first)
//   out = mean_nbr(h @ W2l) + h @ W2r + b2             (transform-first)
// R12: 16-lane-group gathers (128 chains/CU) won (-14us).
// R13: deg merged into prep; latency-bound atomics hide under streaming.
// R14: agg1 fused into fused12 staging (aggb round trip eliminated).
// R15: 4-deep gather MLP -- no effect => gather is request-rate-bound on the
// shared L2-miss/L3 path; per-wave restructuring can't help. combine2 8-lane
// groups gained ~3us (kept).
// R16: occupancy-up via 28-VGPR squeeze REGRESSED (-17%): registers were the
// real resource. Reverted.
// R17: decoupled-lookback scan -> container failure (possible spin-kernel
// hang under graph capture). Dropped; not worth the 3-5us.
// R18: consolidation of best-measured parts: fused12=R14 (52.5us), combine2=
// 8-lane (R15), scan1+scan3 (proven). No experimental structures.
// ---------------------------------------------------------------------------

#define FDIM 128
#define CDIM 32
#define SCAN_CHUNK 1024
#define PSTR 136        // padded LDS row stride in shorts (272B): 2-way bank
                        // aliasing for 16-row frag reads = free (m136)

typedef __attribute__((ext_vector_type(8))) short short8;
typedef __attribute__((ext_vector_type(4))) float f32x4;
typedef unsigned short ushort_t;
typedef unsigned int uint_t;

static __device__ __forceinline__ ushort_t f2bf(float f) {
    uint_t u = __float_as_uint(f);
    u += 0x7fffu + ((u >> 16) & 1u);       // round-to-nearest-even
    return (ushort_t)(u >> 16);
}
static __device__ __forceinline__ float bf2f_lo(uint_t u) {
    return __uint_as_float(u << 16);
}
static __device__ __forceinline__ float bf2f_hi(uint_t u) {
    return __uint_as_float(u & 0xffff0000u);
}

// ---- prep: deg atomics (blocks [0,DB4)) | x->bf16 | W transpose+cvt -------
// deg range FIRST so its latency-bound blocks overlap the streaming ranges.

__global__ __launch_bounds__(256) void prep_kernel(
        const int* __restrict__ dst, int* __restrict__ deg, int E, int n,
        const float* __restrict__ x, uint_t* __restrict__ xb4, long long total8,
        const float* __restrict__ W1l, const float* __restrict__ W1r,
        const float* __restrict__ W2l, const float* __restrict__ W2r,
        ushort_t* __restrict__ w1lt, ushort_t* __restrict__ w1rt,
        ushort_t* __restrict__ w2lt, ushort_t* __restrict__ w2rt,
        int DB4, int CB) {
    int b = (int)blockIdx.x;
    if (b < DB4) {
        int e0 = (b * 256 + threadIdx.x) * 4;
        if (e0 + 3 < E) {
            int4 d4 = *(const int4*)(dst + e0);
            if (d4.x >= 0 && d4.x < n) atomicAdd(&deg[d4.x], 1);
            if (d4.y >= 0 && d4.y < n) atomicAdd(&deg[d4.y], 1);
            if (d4.z >= 0 && d4.z < n) atomicAdd(&deg[d4.z], 1);
            if (d4.w >= 0 && d4.w < n) atomicAdd(&deg[d4.w], 1);
        } else {
            for (int e = e0; e < E; e++) {
                int d = dst[e];
                if (d >= 0 && d < n) atomicAdd(&deg[d], 1);
            }
        }
    } else if (b < DB4 + CB) {
        long long i = (long long)(b - DB4) * 256 + threadIdx.x;
        if (i >= total8) return;
        const float4* p = (const float4*)x + i * 2;
        float4 v0 = p[0], v1 = p[1];
        uint4 o;
        o.x = (uint_t)f2bf(v0.x) | ((uint_t)f2bf(v0.y) << 16);
        o.y = (uint_t)f2bf(v0.z) | ((uint_t)f2bf(v0.w) << 16);
        o.z = (uint_t)f2bf(v1.x) | ((uint_t)f2bf(v1.y) << 16);
        o.w = (uint_t)f2bf(v1.z) | ((uint_t)f2bf(v1.w) << 16);
        ((uint4*)xb4)[i] = o;
    } else {
        int idx = (b - DB4 - CB) * 256 + threadIdx.x;
        const float* w; ushort_t* wt; int Nc, local;
        if (idx < 16384)      { w = W1l; wt = w1lt; Nc = 128; local = idx; }
        else if (idx < 32768) { w = W1r; wt = w1rt; Nc = 128; local = idx - 16384; }
        else if (idx < 36864) { w = W2l; wt = w2lt; Nc = 32;  local = idx - 32768; }
        else if (idx < 40960) { w = W2r; wt = w2rt; Nc = 32;  local = idx - 36864; }
        else return;
        int nn = local >> 7, kk = local & 127;
        wt[nn * 128 + kk] = f2bf(w[kk * Nc + nn]);
    }
}

// ---- hierarchical scan (scan3 re-derives its block offset from partials) --

__global__ __launch_bounds__(256) void scan1_kernel(
        const int* __restrict__ deg, int* __restrict__ partials, int n) {
    __shared__ int red[256];
    int t = threadIdx.x;
    int base = blockIdx.x * SCAN_CHUNK + t * 4;
    int s = 0;
    if (base + 3 < n) {
        int4 v = *(const int4*)(deg + base);
        s = v.x + v.y + v.z + v.w;
    } else {
        for (int i = 0; i < 4; i++) if (base + i < n) s += deg[base + i];
    }
    red[t] = s;
    __syncthreads();
#pragma unroll
    for (int off = 128; off > 0; off >>= 1) {
        if (t < off) red[t] += red[t + off];
        __syncthreads();
    }
    if (t == 0) partials[blockIdx.x] = red[0];
}

// also seeds cursor[i] = rowptr[i] so fill needs no rowptr load
__global__ __launch_bounds__(256) void scan3_kernel(
        const int* __restrict__ deg, const int* __restrict__ partials,
        int* __restrict__ rowptr, int* __restrict__ cursor, int n, int SB) {
    __shared__ int s[256];
    int t = threadIdx.x;
    int pre = (t < SB && t < (int)blockIdx.x) ? partials[t] : 0;
    s[t] = pre;
    __syncthreads();
#pragma unroll
    for (int off = 128; off > 0; off >>= 1) {
        if (t < off) s[t] += s[t + off];
        __syncthreads();
    }
    int blockbase = s[0];
    __syncthreads();

    int base = blockIdx.x * SCAN_CHUNK + t * 4;
    int d0 = 0, d1 = 0, d2 = 0, d3 = 0;
    if (base + 3 < n) {
        int4 v = *(const int4*)(deg + base);
        d0 = v.x; d1 = v.y; d2 = v.z; d3 = v.w;
    } else {
        if (base + 0 < n) d0 = deg[base + 0];
        if (base + 1 < n) d1 = deg[base + 1];
        if (base + 2 < n) d2 = deg[base + 2];
        if (base + 3 < n) d3 = deg[base + 3];
    }
    s[t] = d0 + d1 + d2 + d3;
    __syncthreads();
#pragma unroll
    for (int off = 1; off < 256; off <<= 1) {
        int u = (t >= off) ? s[t - off] : 0;
        __syncthreads();
        s[t] += u;
        __syncthreads();
    }
    int run = blockbase + ((t == 0) ? 0 : s[t - 1]);
    int dd[4] = {d0, d1, d2, d3};
#pragma unroll
    for (int i = 0; i < 4; i++) {
        if (base + i < n) {
            rowptr[base + i] = run;
            cursor[base + i] = run;
            run += dd[i];
        }
    }
}

// ---- fill: 4 edges/thread; cursor pre-seeded with rowptr ------------------

__global__ __launch_bounds__(256) void fill_kernel(
        const int* __restrict__ src, const int* __restrict__ dst,
        int* __restrict__ cursor, int* __restrict__ nbr,
        int E, int n) {
    int e0 = (blockIdx.x * 256 + threadIdx.x) * 4;
    if (e0 + 3 < E) {
        int4 s4 = *(const int4*)(src + e0);
        int4 d4 = *(const int4*)(dst + e0);
        if (d4.x >= 0 && d4.x < n) { int p = atomicAdd(&cursor[d4.x], 1); nbr[p] = s4.x; }
        if (d4.y >= 0 && d4.y < n) { int p = atomicAdd(&cursor[d4.y], 1); nbr[p] = s4.y; }
        if (d4.z >= 0 && d4.z < n) { int p = atomicAdd(&cursor[d4.z], 1); nbr[p] = s4.z; }
        if (d4.w >= 0 && d4.w < n) { int p = atomicAdd(&cursor[d4.w], 1); nbr[p] = s4.w; }
    } else {
        for (int e = e0; e < E; e++) {
            int d = dst[e];
            if (d >= 0 && d < n) { int p = atomicAdd(&cursor[d], 1); nbr[p] = src[e]; }
        }
    }
}

// ---- fused12: gather-agg + layer-1 GEMM + epilogue + layer-2 GEMM ---------
// R14 config (best measured, 52.5us): 512 thr = 8 waves; tile = 64 rows;
// 52KB LDS -> 3 blocks/CU; 40 VGPR. Gather: one row per 16-lane group pass,
// serial rr loop, 2-deep edge walk.

__global__ __launch_bounds__(512, 6) void fused12_kernel(
        const ushort_t* __restrict__ xb,
        const int* __restrict__ rowptr, const int* __restrict__ deg,
        const int* __restrict__ nbr,
        const ushort_t* __restrict__ w1lt, const ushort_t* __restrict__ w1rt,
        const ushort_t* __restrict__ w2lt, const ushort_t* __restrict__ w2rt,
        const float* __restrict__ b1,
        ushort_t* __restrict__ z2b, float* __restrict__ r2, int n) {
    __shared__ ushort_t xs[64 * PSTR];          // x tile; becomes hs after layer 1
    __shared__ ushort_t as_[64 * PSTR];         // agg tile (gathered in-kernel)
    __shared__ ushort_t ws2[2 * 32 * PSTR];     // W2l^T | W2r^T

    const int t    = threadIdx.x;
    const int wave = t >> 6;            // 0..7
    const int lane = t & 63;
    const int quad = lane >> 4;
    const int l16  = lane & 15;
    const int row0 = blockIdx.x * 64;
    const int c1   = wave * 16;         // layer-1 col tile

    const uint_t* xbu = (const uint_t*)xb;

    // stage xb tile: 1024 16B chunks, 2 per thread, coalesced
#pragma unroll
    for (int it = 0; it < 2; it++) {
        int c   = t + it * 512;
        int row = c >> 4, col = c & 15;
        int grow = row0 + row; if (grow >= n) grow = n - 1;   // clamp; stores guarded
        size_t goff = (size_t)grow * FDIM + col * 8;
        *(short8*)(xs + row * PSTR + col * 8) = *(const short8*)(xb + goff);
    }
    // stage W2 (both 32x128): 1024 chunks, 2 per thread
#pragma unroll
    for (int it = 0; it < 2; it++) {
        int c = t + it * 512;
        int m = c >> 9, lo = c & 511;
        int row = lo >> 4, col = lo & 15;
        const ushort_t* sw = m ? w2rt : w2lt;
        *(short8*)(ws2 + (m * 32 + row) * PSTR + col * 8) =
            *(const short8*)(sw + row * 128 + col * 8);
    }

    // gather-aggregate mean_nbr(x) -> as_ : one row per 16-lane group pass,
    // lanes partition the 256B row (uint4/lane), edges walked serially 2-deep.
    const int grp = t >> 4;             // 0..31
    for (int rr = 0; rr < 2; rr++) {
        int row = grp + rr * 32;        // 0..63
        int i = row0 + row;
        float s[8] = {0.f, 0.f, 0.f, 0.f, 0.f, 0.f, 0.f, 0.f};
        int start = 0, d = 0;
        if (i < n) { start = rowptr[i]; d = deg[i]; }
        int e = 0;
        for (; e + 1 < d; e += 2) {
            int j0 = nbr[start + e];
            int j1 = nbr[start + e + 1];
            uint4 u0 = *(const uint4*)(xbu + (size_t)j0 * 64 + l16 * 4);
            uint4 u1 = *(const uint4*)(xbu + (size_t)j1 * 64 + l16 * 4);
            s[0] += bf2f_lo(u0.x) + bf2f_lo(u1.x); s[1] += bf2f_hi(u0.x) + bf2f_hi(u1.x);
            s[2] += bf2f_lo(u0.y) + bf2f_lo(u1.y); s[3] += bf2f_hi(u0.y) + bf2f_hi(u1.y);
            s[4] += bf2f_lo(u0.z) + bf2f_lo(u1.z); s[5] += bf2f_hi(u0.z) + bf2f_hi(u1.z);
            s[6] += bf2f_lo(u0.w) + bf2f_lo(u1.w); s[7] += bf2f_hi(u0.w) + bf2f_hi(u1.w);
        }
        if (e < d) {
            int j = nbr[start + e];
            uint4 u = *(const uint4*)(xbu + (size_t)j * 64 + l16 * 4);
            s[0] += bf2f_lo(u.x); s[1] += bf2f_hi(u.x);
            s[2] += bf2f_lo(u.y); s[3] += bf2f_hi(u.y);
            s[4] += bf2f_lo(u.z); s[5] += bf2f_hi(u.z);
            s[6] += bf2f_lo(u.w); s[7] += bf2f_hi(u.w);
        }
        float inv = 1.0f / (float)(d > 0 ? d : 1);
        uint4 o;
        o.x = (uint_t)f2bf(s[0] * inv) | ((uint_t)f2bf(s[1] * inv) << 16);
        o.y = (uint_t)f2bf(s[2] * inv) | ((uint_t)f2bf(s[3] * inv) << 16);
        o.z = (uint_t)f2bf(s[4] * inv) | ((uint_t)f2bf(s[5] * inv) << 16);
        o.w = (uint_t)f2bf(s[6] * inv) | ((uint_t)f2bf(s[7] * inv) << 16);
        *(uint4*)(as_ + row * PSTR + l16 * 8) = o;   // 272B rows, 16B aligned
    }

    // W1 B-frags for this wave's 16 cols -> registers (L2-resident)
    short8 bl1[4], br1[4];
#pragma unroll
    for (int k = 0; k < 4; k++) {
        size_t woff = (size_t)(c1 + l16) * FDIM + k * 32 + quad * 8;
        bl1[k] = *(const short8*)(w1lt + woff);
        br1[k] = *(const short8*)(w1rt + woff);
    }
    float b1c = b1[c1 + l16];

    __syncthreads();

    // ---- layer 1: A-frags from LDS ----
    f32x4 acc1[4];
#pragma unroll
    for (int r = 0; r < 4; r++) acc1[r] = (f32x4){0.f, 0.f, 0.f, 0.f};

#pragma unroll
    for (int k = 0; k < 4; k++) {
        short8 a1[4], a2[4];
#pragma unroll
        for (int r = 0; r < 4; r++) {
            int lro = (r * 16 + l16) * PSTR + k * 32 + quad * 8;
            a1[r] = *(const short8*)(as_ + lro);
            a2[r] = *(const short8*)(xs  + lro);
        }
#pragma unroll
        for (int r = 0; r < 4; r++) {
            acc1[r] = __builtin_amdgcn_mfma_f32_16x16x32_bf16(a1[r], bl1[k], acc1[r], 0, 0, 0);
            acc1[r] = __builtin_amdgcn_mfma_f32_16x16x32_bf16(a2[r], br1[k], acc1[r], 0, 0, 0);
        }
    }

    __syncthreads();          // all waves done reading xs before hs overwrite

    // epilogue -> hs (= xs). C/D: col = l16, row = quad*4 + reg.
    ushort_t* hs = xs;
#pragma unroll
    for (int r = 0; r < 4; r++)
#pragma unroll
        for (int reg = 0; reg < 4; reg++) {
            int lrow = r * 16 + quad * 4 + reg;
            float v = acc1[r][reg] + b1c;
            v = v > 0.f ? v : 0.f;
            hs[lrow * PSTR + c1 + l16] = f2bf(v);
        }

    __syncthreads();

    // ---- layer 2 ----
    const int rs = (wave >> 1) * 16;    // row sub-tile
    const int c2 = (wave & 1) * 16;     // col tile
    f32x4 a2l = (f32x4){0.f, 0.f, 0.f, 0.f};
    f32x4 a2r = (f32x4){0.f, 0.f, 0.f, 0.f};
#pragma unroll
    for (int k = 0; k < 4; k++) {
        short8 ah = *(const short8*)(hs  + (rs + l16) * PSTR + k * 32 + quad * 8);
        short8 wl = *(const short8*)(ws2 + (c2 + l16) * PSTR + k * 32 + quad * 8);
        short8 wr = *(const short8*)(ws2 + (32 + c2 + l16) * PSTR + k * 32 + quad * 8);
        a2l = __builtin_amdgcn_mfma_f32_16x16x32_bf16(ah, wl, a2l, 0, 0, 0);
        a2r = __builtin_amdgcn_mfma_f32_16x16x32_bf16(ah, wr, a2r, 0, 0, 0);
    }
#pragma unroll
    for (int reg = 0; reg < 4; reg++) {
        int grow = row0 + rs + quad * 4 + reg;
        if (grow < n) {
            z2b[(size_t)grow * CDIM + c2 + l16] = f2bf(a2l[reg]);
            r2 [(size_t)grow * CDIM + c2 + l16] = a2r[reg];
        }
    }
}

// ---- combine2: out = inv * sum_j z2b[j] + r2 + b2 -------------------------
// ONE NODE PER 8-LANE GROUP (32 chains / 256-thr block): lanes partition the
// 64B row (uint2/lane), serial 2-deep edge walk, no reduce; float4/lane
// epilogue. Per-column accumulation order identical to R14.

__global__ __launch_bounds__(256) void combine2_kernel(
        const uint_t* __restrict__ z2bu /* N x 16 uints */,
        const int* __restrict__ rowptr, const int* __restrict__ deg,
        const int* __restrict__ nbr, const float* __restrict__ b2,
        const float* __restrict__ r2, float* __restrict__ out, int n) {
    int t = threadIdx.x;
    int i = blockIdx.x * 32 + (t >> 3);
    if (i >= n) return;
    int l8 = t & 7;
    int start = rowptr[i];
    int d     = deg[i];
    float s0 = 0.f, s1 = 0.f, s2 = 0.f, s3 = 0.f;
    int e = 0;
    for (; e + 1 < d; e += 2) {
        int j0 = nbr[start + e];
        int j1 = nbr[start + e + 1];
        uint2 u0 = *(const uint2*)(z2bu + (size_t)j0 * 16 + l8 * 2);
        uint2 u1 = *(const uint2*)(z2bu + (size_t)j1 * 16 + l8 * 2);
        s0 += bf2f_lo(u0.x) + bf2f_lo(u1.x);
        s1 += bf2f_hi(u0.x) + bf2f_hi(u1.x);
        s2 += bf2f_lo(u0.y) + bf2f_lo(u1.y);
        s3 += bf2f_hi(u0.y) + bf2f_hi(u1.y);
    }
    if (e < d) {
        int j = nbr[start + e];
        uint2 u = *(const uint2*)(z2bu + (size_t)j * 16 + l8 * 2);
        s0 += bf2f_lo(u.x);
        s1 += bf2f_hi(u.x);
        s2 += bf2f_lo(u.y);
        s3 += bf2f_hi(u.y);
    }
    float inv = 1.0f / (float)(d > 0 ? d : 1);
    float4 rr = *(const float4*)(r2 + (size_t)i * CDIM + l8 * 4);
    float4 bb = *(const float4*)(b2 + l8 * 4);
    float4 o;
    o.x = s0 * inv + rr.x + bb.x;
    o.y = s1 * inv + rr.y + bb.y;
    o.z = s2 * inv + rr.z + bb.z;
    o.w = s3 * inv + rr.w + bb.w;
    *(float4*)(out + (size_t)i * CDIM + l8 * 4) = o;
}

// ---------------------------------------------------------------------------

extern "C" void kernel_launch(void* const* d_in, const int* in_sizes, int n_in,
                              void* d_out, int out_size, void* d_ws, size_t ws_size,
                              hipStream_t stream) {
    const float* x   = (const float*)d_in[0];
    const int*   ei  = (const int*)d_in[1];     // int64 in ref -> int32 here
    const float* W1l = (const float*)d_in[2];
    const float* b1  = (const float*)d_in[3];
    const float* W1r = (const float*)d_in[4];
    const float* W2l = (const float*)d_in[5];
    const float* b2  = (const float*)d_in[6];
    const float* W2r = (const float*)d_in[7];

    const int N = in_sizes[0] / FDIM;
    const int E = in_sizes[1] / 2;
    const int* src = ei;
    const int* dst = ei + E;

    char* p = (char*)d_ws;
    int*      deg      = (int*)p;      p += (size_t)N * sizeof(int);
    int*      cursor   = (int*)p;      p += (size_t)N * sizeof(int);
    int*      rowptr   = (int*)p;      p += (size_t)N * sizeof(int);
    int*      partials = (int*)p;      p += 256 * sizeof(int);
    ushort_t* w1lt     = (ushort_t*)p; p += FDIM * FDIM * sizeof(ushort_t);
    ushort_t* w1rt     = (ushort_t*)p; p += FDIM * FDIM * sizeof(ushort_t);
    ushort_t* w2lt     = (ushort_t*)p; p += FDIM * CDIM * sizeof(ushort_t);
    ushort_t* w2rt     = (ushort_t*)p; p += FDIM * CDIM * sizeof(ushort_t);
    int*      nbr      = (int*)p;      p += (size_t)((E + 3) / 4 * 4) * sizeof(int);
    ushort_t* xb       = (ushort_t*)p; p += (size_t)N * FDIM * sizeof(ushort_t);
    ushort_t* z2b      = (ushort_t*)p; p += (size_t)N * CDIM * sizeof(ushort_t);
    float*    r2       = (float*)p;    p += (size_t)N * CDIM * sizeof(float);

    const int SB = (N + SCAN_CHUNK - 1) / SCAN_CHUNK;
    const long long total8 = (long long)N * FDIM / 8;
    const int CB = (int)((total8 + 255) / 256);
    const int E4 = (E + 3) / 4;
    const int DB4 = (E4 + 255) / 256;
    const int WB = (40960 + 255) / 256;

    hipMemsetAsync(deg, 0, (size_t)N * sizeof(int), stream);  // cursor seeded by scan3

    prep_kernel <<<DB4 + CB + WB, 256, 0, stream>>>(dst, deg, E, N,
                                                    x, (uint_t*)xb, total8,
                                                    W1l, W1r, W2l, W2r,
                                                    w1lt, w1rt, w2lt, w2rt, DB4, CB);
    scan1_kernel<<<SB, 256, 0, stream>>>(deg, partials, N);
    scan3_kernel<<<SB, 256, 0, stream>>>(deg, partials, rowptr, cursor, N, SB);
    fill_kernel <<<DB4, 256, 0, stream>>>(src, dst, cursor, nbr, E, N);

    fused12_kernel<<<(N + 63) / 64, 512, 0, stream>>>(xb, rowptr, deg, nbr,
                                                      w1lt, w1rt, w2lt, w2rt,
                                                      b1, z2b, r2, N);
    combine2_kernel<<<(N + 31) / 32, 256, 0, stream>>>((const uint_t*)z2b, rowptr, deg, nbr,
                                                       b2, r2, (float*)d_out, N);
}